// Round 4
// baseline (1453.340 us; speedup 1.0000x reference)
//
#include <hip/hip_runtime.h>
#include <cstddef>

#define B_    8
#define H_    32
#define W_    32
#define L_    6
#define R_    384
#define NH_   6
#define DH_   64
#define M_    1365
#define MPAD_ 1408
#define NE_   2304
#define HID_  9216
#define NROW_ 49152   // B*H*W*L
#define BMR_  10920   // B*M

typedef __bf16 bf16x8 __attribute__((ext_vector_type(8)));
typedef float  f32x4  __attribute__((ext_vector_type(4)));
typedef unsigned short us;

__device__ __forceinline__ unsigned short f2b(float f){
  unsigned u = __float_as_uint(f);
  u = (u + 0x7FFFu + ((u >> 16) & 1u)) >> 16;
  return (unsigned short)u;
}

__device__ __forceinline__ void gload16(const unsigned short* g, unsigned short* l){
  __builtin_amdgcn_global_load_lds(
      (const __attribute__((address_space(1))) unsigned int*)g,
      (__attribute__((address_space(3))) unsigned int*)l,
      16, 0, 0);
}

__device__ __forceinline__ float wsum(float s){
  #pragma unroll
  for (int o = 32; o > 0; o >>= 1) s += __shfl_xor(s, o, 64);
  return s;
}

__device__ __forceinline__ float rmax16(float v){
  v = fmaxf(v, __shfl_xor(v, 1, 64));
  v = fmaxf(v, __shfl_xor(v, 2, 64));
  v = fmaxf(v, __shfl_xor(v, 4, 64));
  v = fmaxf(v, __shfl_xor(v, 8, 64));
  return v;
}
__device__ __forceinline__ float rsum16(float v){
  v += __shfl_xor(v, 1, 64);
  v += __shfl_xor(v, 2, 64);
  v += __shfl_xor(v, 4, 64);
  v += __shfl_xor(v, 8, 64);
  return v;
}

// gelu(tanh approx) == x * sigmoid(1.5957691216*(x + 0.044715*x^3)) exactly.
__device__ __forceinline__ float gelu_fast(float x){
  float t = fmaf(0.07135482f * x, x * x, 1.5957691216f * x);
  return x / (1.0f + __expf(-t));
}

// ---------------- LN1 + scaled atomic scatter into uniq (B,M,R) ----------------
__global__ __launch_bounds__(256) void k_ln1_scatter(
    const float* __restrict__ x, const float* __restrict__ lw,
    const float* __restrict__ lb, float* __restrict__ uniq){
  int row  = blockIdx.x * 4 + (threadIdx.x >> 6);
  int lane = threadIdx.x & 63;
  int l  = row % 6;
  int hw = (row / 6) & 1023;
  int b  = row / 6144;
  int h = hw >> 5, w = hw & 31;
  const float* xr = x + (size_t)row * R_;
  float v[6]; float s = 0.f;
  #pragma unroll
  for (int i = 0; i < 6; i++){ v[i] = xr[lane + i*64]; s += v[i]; }
  s = wsum(s);
  float mu = s * (1.f/384.f);
  float qq = 0.f;
  #pragma unroll
  for (int i = 0; i < 6; i++){ float d = v[i]-mu; qq += d*d; }
  qq = wsum(qq);
  float rs = rsqrtf(qq * (1.f/384.f) + 1e-5f);
  int off = (4096 - (4096 >> (2*l))) / 3;
  int id  = off + (h >> l) * (32 >> l) + (w >> l);
  float invc = 1.f / (float)(1 << (2*l));
  float* ur = uniq + ((size_t)b * M_ + id) * R_;
  #pragma unroll
  for (int i = 0; i < 6; i++){
    int r = lane + i*64;
    float ln = (v[i]-mu)*rs*lw[r] + lb[r];
    atomicAdd(&ur[r], ln * invc);
  }
}

// ---------------- fp32 -> bf16 convert ----------------
__global__ void k_cvt(const float* __restrict__ src, unsigned short* __restrict__ dst, int n){
  int i = blockIdx.x * 256 + threadIdx.x;
  if (i < n) dst[i] = f2b(src[i]);
}

// ---------------- transpose + convert: src K x N fp32 -> dst N x K bf16 ----------------
__global__ void k_tcvt(const float* __restrict__ src, unsigned short* __restrict__ dst,
                       int K, int N){
  __shared__ float t[32][33];
  int n0 = blockIdx.x * 32, k0 = blockIdx.y * 32;
  int tx = threadIdx.x, ty = threadIdx.y;
  #pragma unroll
  for (int i = 0; i < 4; i++)
    t[ty + i*8][tx] = src[(size_t)(k0 + ty + i*8) * N + n0 + tx];
  __syncthreads();
  #pragma unroll
  for (int i = 0; i < 4; i++)
    dst[(size_t)(n0 + ty + i*8) * K + k0 + tx] = f2b(t[tx][ty + i*8]);
}

// ---------------- bf16 MFMA GEMM (128x128 tile, 2-phase) ----------------
// Kept for the small GEMMs (QKV EPI=5, attn-out EPI=0) where M/N aren't %256.
template<int EPI>
__global__ __launch_bounds__(256) void k_gemm(
    const unsigned short* __restrict__ A,   // M x K bf16
    const unsigned short* __restrict__ Bt,  // N x K bf16
    const float* __restrict__ bias,         // N
    void* __restrict__ Cout,
    const float* __restrict__ res,
    void* __restrict__ aux1, void* __restrict__ aux2,
    int Mtot, int N, int K){
  __shared__ unsigned short As[128*64];
  __shared__ unsigned short Bs[128*64];
  int m0 = blockIdx.x * 128, n0 = blockIdx.y * 128;
  int tid  = threadIdx.x;
  int wv   = tid >> 6, lane = tid & 63;
  int quad = lane >> 4, l16 = lane & 15;
  int wm = (wv >> 1) * 64, wn = (wv & 1) * 64;
  int lr = lane >> 3;          // row within 8-row chunk
  int lc = (lane & 7) * 8;     // short col within 64-col row
  f32x4 acc[4][4];
  #pragma unroll
  for (int a = 0; a < 4; a++)
    #pragma unroll
    for (int bidx = 0; bidx < 4; bidx++) acc[a][bidx] = 0.f;

  for (int k0 = 0; k0 < K; k0 += 64){
    #pragma unroll
    for (int j = 0; j < 4; j++){
      int c = wv*4 + j;            // chunk 0..15, 8 rows each
      int rowa = c*8 + lr;
      int gm = m0 + rowa; if (gm >= Mtot) gm = Mtot - 1;
      gload16(A + (size_t)gm * K + k0 + lc, &As[c*512]);
      int gn = n0 + rowa;          // N multiple of 128
      gload16(Bt + (size_t)gn * K + k0 + lc, &Bs[c*512]);
    }
    asm volatile("s_waitcnt vmcnt(0)" ::: "memory");
    __syncthreads();
    #pragma unroll
    for (int ko = 0; ko < 2; ko++){
      bf16x8 af[4], bfr[4];
      #pragma unroll
      for (int t = 0; t < 4; t++){
        af[t]  = *(const bf16x8*)(&As[(wm + t*16 + l16)*64 + ko*32 + quad*8]);
        bfr[t] = *(const bf16x8*)(&Bs[(wn + t*16 + l16)*64 + ko*32 + quad*8]);
      }
      #pragma unroll
      for (int mt = 0; mt < 4; mt++)
        #pragma unroll
        for (int nt = 0; nt < 4; nt++)
          acc[mt][nt] = __builtin_amdgcn_mfma_f32_16x16x32_bf16(
              af[mt], bfr[nt], acc[mt][nt], 0, 0, 0);
    }
    __syncthreads();
  }
  #pragma unroll
  for (int mt = 0; mt < 4; mt++){
    #pragma unroll
    for (int i = 0; i < 4; i++){
      int row = m0 + wm + mt*16 + quad*4 + i;
      if (row >= Mtot) continue;
      #pragma unroll
      for (int nt = 0; nt < 4; nt++){
        int col = n0 + wn + nt*16 + l16;
        size_t idx = (size_t)row * N + col;
        float vv = acc[mt][nt][i] + bias[col];
        if (EPI == 5){
          int bb = row / M_;
          int mm = row - bb * M_;
          if (col < 384){
            ((unsigned short*)Cout)[(size_t)row * R_ + col] = f2b(vv);
          } else if (col < 768){
            ((unsigned short*)aux1)[(size_t)row * R_ + col - 384] = f2b(vv);
          } else {
            int c2 = col - 768;
            int hh = c2 >> 6, dd = c2 & 63;
            ((unsigned short*)aux2)[(((size_t)(bb*NH_ + hh))*DH_ + dd)*MPAD_ + mm] = f2b(vv);
          }
        } else {
          ((float*)Cout)[idx] = vv;
        }
      }
    }
  }
}

// ================= 256x256 4-phase (m201 cadence) bf16 GEMM =================
// Faithful port of the verified 8-phase/2-K-tile template: per phase
// {ds_read phase's A-row-pair (+ B frags in phase 0); stage ONE half-tile;
//  s_barrier; lgkmcnt(0); setprio(1); 16 MFMA (ko-outer, no adjacent
//  same-acc deps); setprio(0); s_barrier}. vmcnt(4) counted, only in phase 3
//  (B(t+2) stays in flight). T2 granule swizzle unchanged. 8 waves (2Mx4N),
//  per-wave C = 128x64. LDS 128 KiB -> 1 block/CU.
// REQUIRES: Mtot%256==0, N%256==0, kLen%64==0, (kLen/64)%2==0.
// EPI 1: bias+gelu -> bf16.  EPI 3: fp32 atomicAdd into pre-initialized Cout.

__device__ __forceinline__ void stage_half(const unsigned short* __restrict__ g,
                                           unsigned short* l, int K){
  int tid = threadIdx.x;
  int w  = tid >> 6;                  // wave 0..7 -> rows w*16..w*16+15
  int ln = tid & 63;
  int rw = ln >> 3;                   // row within 8-row chunk (== row&7)
  int cs = ((ln & 7) ^ rw) * 8;       // swizzled short-col (pre-swizzled source)
  gload16(g + (size_t)(w*16 + rw)     * K + cs, l + (w*16)*64);
  gload16(g + (size_t)(w*16 + 8 + rw) * K + cs, l + (w*16 + 8)*64);
}

__device__ __forceinline__ bf16x8 ldsfrag(const unsigned short* base, int row, int ko, int quad){
  int g = ((ko << 2) + quad) ^ (row & 7);   // un-swizzle: slot g holds granule g^(row&7)
  return *(const bf16x8*)(base + row*64 + g*8);
}

#define SB0()  __builtin_amdgcn_sched_barrier(0)
#define MFMA16(A8, B8, C4) __builtin_amdgcn_mfma_f32_16x16x32_bf16(A8, B8, C4, 0, 0, 0)

// One phase: row-pair P (compile-time), optional stage stmt, optional tail stmt.
#define PHASE(P, STAGE_STMT, TAIL_STMT)                                          \
  { bf16x8 aL0 = ldsfrag(curA, wr*128 + (2*(P))*16   + l16, 0, quad);            \
    bf16x8 aH0 = ldsfrag(curA, wr*128 + (2*(P))*16   + l16, 1, quad);            \
    bf16x8 aL1 = ldsfrag(curA, wr*128 + (2*(P)+1)*16 + l16, 0, quad);            \
    bf16x8 aH1 = ldsfrag(curA, wr*128 + (2*(P)+1)*16 + l16, 1, quad);            \
    STAGE_STMT;                                                                  \
    SB0();                                                                       \
    __builtin_amdgcn_s_barrier();                                                \
    asm volatile("s_waitcnt lgkmcnt(0)" ::: "memory");                           \
    SB0();                                                                       \
    __builtin_amdgcn_s_setprio(1);                                               \
    _Pragma("unroll")                                                            \
    for (int nt = 0; nt < 4; nt++)                                               \
      acc[2*(P)][nt]   = MFMA16(aL0, bfr[nt][0], acc[2*(P)][nt]);                \
    _Pragma("unroll")                                                            \
    for (int nt = 0; nt < 4; nt++)                                               \
      acc[2*(P)+1][nt] = MFMA16(aL1, bfr[nt][0], acc[2*(P)+1][nt]);              \
    _Pragma("unroll")                                                            \
    for (int nt = 0; nt < 4; nt++)                                               \
      acc[2*(P)][nt]   = MFMA16(aH0, bfr[nt][1], acc[2*(P)][nt]);                \
    _Pragma("unroll")                                                            \
    for (int nt = 0; nt < 4; nt++)                                               \
      acc[2*(P)+1][nt] = MFMA16(aH1, bfr[nt][1], acc[2*(P)+1][nt]);              \
    __builtin_amdgcn_s_setprio(0);                                               \
    TAIL_STMT;                                                                   \
    SB0();                                                                       \
    __builtin_amdgcn_s_barrier();                                                \
    SB0(); }

// One K-tile with compile-time buffer index.
#define KTILE(CURBUF)                                                            \
  { us* curA = &lds8[CURBUF][0];                                                 \
    us* curB = curA + 16384;                                                     \
    us* nxtA = &lds8[(CURBUF) ^ 1][0];                                           \
    bool st1 = (t + 1 < NT), st2 = (t + 2 < NT);                                 \
    const us* An = Ab + (size_t)(t + 1) * 64;                                    \
    const us* Bn = Bb + (size_t)(t + 2) * 64;                                    \
    bf16x8 bfr[4][2];                                                            \
    _Pragma("unroll")                                                            \
    for (int nt = 0; nt < 4; nt++){                                              \
      bfr[nt][0] = ldsfrag(curB, wc*64 + nt*16 + l16, 0, quad);                  \
      bfr[nt][1] = ldsfrag(curB, wc*64 + nt*16 + l16, 1, quad);                  \
    }                                                                            \
    PHASE(0, { if (st1) stage_half(An,          nxtA,        Kfull); }, {});     \
    PHASE(1, { if (st1) stage_half(An + 128*KS, nxtA + 8192, Kfull); }, {});     \
    PHASE(2, { if (st2) stage_half(Bn,          curB,        Kfull); }, {});     \
    PHASE(3, { if (st2) stage_half(Bn + 128*KS, curB + 8192, Kfull); },          \
             { if (st1){                                                         \
                 if (st2) asm volatile("s_waitcnt vmcnt(4)" ::: "memory");       \
                 else     asm volatile("s_waitcnt vmcnt(0)" ::: "memory");       \
               } });                                                             \
    ++t; }

template<int EPI>
__global__ __launch_bounds__(512, 2) void k_gemm8(
    const unsigned short* __restrict__ A,   // Mtot x Kfull bf16
    const unsigned short* __restrict__ Bt,  // N x Kfull bf16
    const float* __restrict__ bias,
    void* __restrict__ Cout,
    int Mtot, int N, int Kfull, int kLen){
  __shared__ unsigned short lds8[2][32768];  // [buf][A 256x64 | B 256x64]

  int m0 = blockIdx.x * 256, n0 = blockIdx.y * 256;
  int k0 = blockIdx.z * kLen;
  int NT = kLen >> 6;                        // must be even
  const size_t KS = (size_t)Kfull;
  const us* Ab = A  + (size_t)m0 * KS + k0;
  const us* Bb = Bt + (size_t)n0 * KS + k0;
  int tid = threadIdx.x, wv = tid >> 6, lane = tid & 63;
  int quad = lane >> 4, l16 = lane & 15;
  int wr = wv >> 2, wc = wv & 3;       // 2M x 4N wave grid

  f32x4 acc[8][4];
  #pragma unroll
  for (int a = 0; a < 8; a++)
    #pragma unroll
    for (int b = 0; b < 4; b++) acc[a][b] = 0.f;

  // ---- prologue: tile0 all 4 halves into buf0; tile1 B-halves into buf1 ----
  stage_half(Bb,               &lds8[0][16384],        Kfull);  // H(0, B0)
  stage_half(Bb + 128*KS,      &lds8[0][16384 + 8192], Kfull);  // H(0, B1)
  stage_half(Ab,               &lds8[0][0],            Kfull);  // H(0, A0)
  stage_half(Ab + 128*KS,      &lds8[0][8192],         Kfull);  // H(0, A1)
  if (NT > 1){
    stage_half(Bb + 64,             &lds8[1][16384],        Kfull);  // H(1, B0)
    stage_half(Bb + 128*KS + 64,    &lds8[1][16384 + 8192], Kfull);  // H(1, B1)
    asm volatile("s_waitcnt vmcnt(4)" ::: "memory");
  } else {
    asm volatile("s_waitcnt vmcnt(0)" ::: "memory");
  }
  __builtin_amdgcn_s_barrier();
  SB0();

  int t = 0;
  while (t < NT){
    KTILE(0);
    KTILE(1);
  }

  // ---- epilogue ----
  #pragma unroll
  for (int mt = 0; mt < 8; mt++){
    #pragma unroll
    for (int i = 0; i < 4; i++){
      int row = m0 + wr*128 + mt*16 + quad*4 + i;
      #pragma unroll
      for (int nt = 0; nt < 4; nt++){
        int col = n0 + wc*64 + nt*16 + l16;
        size_t idx = (size_t)row * N + col;
        float vv = acc[mt][nt][i];
        if (EPI == 1){
          ((unsigned short*)Cout)[idx] = f2b(gelu_fast(vv + bias[col]));
        } else {
          atomicAdd(&((float*)Cout)[idx], vv);
        }
      }
    }
  }
}

// ---------------- bf16 MFMA flash attention over M=1365 nodes ----------------
__global__ __launch_bounds__(256) void k_attn(
    const unsigned short* __restrict__ qb, const unsigned short* __restrict__ kb,
    const unsigned short* __restrict__ vtb, unsigned short* __restrict__ ob){
  __shared__ unsigned short Ks[64][64];
  __shared__ unsigned short Vt[64][64];
  __shared__ unsigned short Ps[4][16][64];
  int qt = blockIdx.x, bh = blockIdx.y;
  int b = bh / NH_, h = bh % NH_;
  int tid = threadIdx.x, wv = tid >> 6, lane = tid & 63;
  int quad = lane >> 4, l16 = lane & 15;

  int qm = qt*64 + wv*16 + l16;
  const unsigned short* qrow = qb + (size_t)(b*M_ + qm)*R_ + h*DH_;
  bf16x8 aq0 = *(const bf16x8*)(qrow + quad*8);
  bf16x8 aq1 = *(const bf16x8*)(qrow + 32 + quad*8);

  f32x4 oacc[4];
  #pragma unroll
  for (int db = 0; db < 4; db++) oacc[db] = 0.f;
  float mi[4], li[4];
  #pragma unroll
  for (int i = 0; i < 4; i++){ mi[i] = -1e30f; li[i] = 0.f; }

  for (int kt = 0; kt < 22; kt++){
    #pragma unroll
    for (int i = 0; i < 2; i++){
      int c = tid + i*256;
      int rowa = c >> 3, colc = (c & 7) * 8;
      *(uint4*)(&Ks[rowa][colc]) =
        *(const uint4*)(kb + (size_t)(b*M_ + kt*64 + rowa)*R_ + h*DH_ + colc);
      *(uint4*)(&Vt[rowa][colc]) =
        *(const uint4*)(vtb + ((size_t)bh*DH_ + rowa)*MPAD_ + kt*64 + colc);
    }
    __syncthreads();

    f32x4 s[4];
    #pragma unroll
    for (int nb = 0; nb < 4; nb++){
      s[nb] = 0.f;
      bf16x8 bk0 = *(const bf16x8*)(&Ks[nb*16 + l16][quad*8]);
      bf16x8 bk1 = *(const bf16x8*)(&Ks[nb*16 + l16][32 + quad*8]);
      s[nb] = __builtin_amdgcn_mfma_f32_16x16x32_bf16(aq0, bk0, s[nb], 0, 0, 0);
      s[nb] = __builtin_amdgcn_mfma_f32_16x16x32_bf16(aq1, bk1, s[nb], 0, 0, 0);
    }

    #pragma unroll
    for (int i = 0; i < 4; i++){
      float val[4];
      float mx = -1e30f;
      #pragma unroll
      for (int nb = 0; nb < 4; nb++){
        int gc = kt*64 + nb*16 + l16;
        val[nb] = (gc < M_) ? s[nb][i] * 0.125f : -1e30f;
        mx = fmaxf(mx, val[nb]);
      }
      mx = rmax16(mx);
      float mnew = fmaxf(mi[i], mx);
      float alpha = __expf(mi[i] - mnew);
      float rs = 0.f;
      #pragma unroll
      for (int nb = 0; nb < 4; nb++){
        float p = __expf(val[nb] - mnew);
        rs += p;
        Ps[wv][quad*4 + i][nb*16 + l16] = f2b(p);
      }
      rs = rsum16(rs);
      li[i] = li[i]*alpha + rs;
      mi[i] = mnew;
      #pragma unroll
      for (int db = 0; db < 4; db++) oacc[db][i] *= alpha;
    }

    #pragma unroll
    for (int ko = 0; ko < 2; ko++){
      bf16x8 ap = *(const bf16x8*)(&Ps[wv][l16][ko*32 + quad*8]);
      #pragma unroll
      for (int db = 0; db < 4; db++){
        bf16x8 bv = *(const bf16x8*)(&Vt[db*16 + l16][ko*32 + quad*8]);
        oacc[db] = __builtin_amdgcn_mfma_f32_16x16x32_bf16(ap, bv, oacc[db], 0, 0, 0);
      }
    }
    __syncthreads();
  }

  #pragma unroll
  for (int i = 0; i < 4; i++){
    int gm = qt*64 + wv*16 + quad*4 + i;
    if (gm < M_){
      float il = 1.f / li[i];
      #pragma unroll
      for (int db = 0; db < 4; db++)
        ob[(size_t)(b*M_ + gm)*R_ + h*DH_ + db*16 + l16] = f2b(oacc[db][i] * il);
    }
  }
}

// ---- scatter attn_out + residual -> xres; out = xres + b2 (MLP2 base); LN2 -> flat bf16 ----
__global__ __launch_bounds__(256) void k_scatter_ln2(
    const float* __restrict__ x, const float* __restrict__ attn,
    const float* __restrict__ lw, const float* __restrict__ lb,
    const float* __restrict__ b2,
    float* __restrict__ xres, unsigned short* __restrict__ flatb){
  int row  = blockIdx.x * 4 + (threadIdx.x >> 6);
  int lane = threadIdx.x & 63;
  int l  = row % 6;
  int hw = (row / 6) & 1023;
  int b  = row / 6144;
  int h = hw >> 5, w = hw & 31;
  int off = (4096 - (4096 >> (2*l))) / 3;
  int id  = off + (h >> l) * (32 >> l) + (w >> l);
  const float* ar = attn + ((size_t)b * M_ + id) * R_;
  const float* xr = x + (size_t)row * R_;
  float* orow = xres + (size_t)row * R_;
  float vv[6]; float s = 0.f;
  #pragma unroll
  for (int i = 0; i < 6; i++){
    int r = lane + i*64;
    float t = xr[r] + ar[r];
    vv[i] = t; s += t;
    orow[r] = t + b2[l*R_ + r];     // pre-fold bias: MLP2 partials atomicAdd onto this
  }
  s = wsum(s);
  float mu = s * (1.f/384.f);
  float qq = 0.f;
  #pragma unroll
  for (int i = 0; i < 6; i++){ float d = vv[i]-mu; qq += d*d; }
  qq = wsum(qq);
  float rs = rsqrtf(qq * (1.f/384.f) + 1e-5f);
  unsigned short* fr = flatb + (size_t)row * R_;
  #pragma unroll
  for (int i = 0; i < 6; i++){
    int r = lane + i*64;
    fr[r] = f2b((vv[i]-mu)*rs*lw[r] + lb[r]);
  }
}

extern "C" void kernel_launch(void* const* d_in, const int* in_sizes, int n_in,
                              void* d_out, int out_size, void* d_ws, size_t ws_size,
                              hipStream_t stream){
  const float* x    = (const float*)d_in[0];
  const float* ln1w = (const float*)d_in[1];
  const float* ln1b = (const float*)d_in[2];
  const float* ln2w = (const float*)d_in[3];
  const float* ln2b = (const float*)d_in[4];
  const float* wq   = (const float*)d_in[5];
  const float* bq   = (const float*)d_in[6];
  const float* wk   = (const float*)d_in[7];
  const float* bk   = (const float*)d_in[8];
  const float* wvv  = (const float*)d_in[9];
  const float* bv   = (const float*)d_in[10];
  const float* wo   = (const float*)d_in[11];
  const float* bo   = (const float*)d_in[12];
  const float* w1   = (const float*)d_in[13];
  const float* b1   = (const float*)d_in[14];
  const float* w2   = (const float*)d_in[15];
  const float* b2   = (const float*)d_in[16];
  float* out = (float*)d_out;

  // ---- workspace layout ----
  char* ws = (char*)d_ws;
  unsigned short* h1b = (unsigned short*)ws;                     // 8192*9216 bf16 (reuses region A)
  unsigned short* qb  = (unsigned short*)ws;
  unsigned short* kb  = qb + (size_t)BMR_ * R_;
  unsigned short* vtb = kb + (size_t)BMR_ * R_;
  unsigned short* ob  = vtb + (size_t)B_ * NH_ * DH_ * MPAD_;
  float* attn_o = (float*)(ob + (size_t)BMR_ * R_);
  size_t regA = ((size_t)8192 * HID_ * 2 + 255) & ~(size_t)255;
  char* p = ws + regA;
  float* uniqf = (float*)p;                   p += (size_t)BMR_ * R_ * 4;
  unsigned short* uniqb = (unsigned short*)p; p += (size_t)BMR_ * R_ * 2;
  unsigned short* wqkvt = (unsigned short*)p; p += (size_t)3 * R_ * R_ * 2;
  unsigned short* wot = (unsigned short*)p;   p += (size_t)R_ * R_ * 2;
  unsigned short* w1t = (unsigned short*)p;   p += (size_t)NE_ * HID_ * 2;
  unsigned short* w2t = (unsigned short*)p;   p += (size_t)NE_ * HID_ * 2;
  unsigned short* flatb = (unsigned short*)p; p += (size_t)NROW_ * R_ * 2;
  float* bqkv = (float*)p;                    p += (size_t)3 * R_ * 4;

  hipMemsetAsync(uniqf, 0, (size_t)BMR_ * R_ * 4, stream);
  hipMemsetAsync(vtb, 0, (size_t)B_ * NH_ * DH_ * MPAD_ * 2, stream);
  hipMemcpyAsync(bqkv,        bq, R_*4, hipMemcpyDeviceToDevice, stream);
  hipMemcpyAsync(bqkv + R_,   bk, R_*4, hipMemcpyDeviceToDevice, stream);
  hipMemcpyAsync(bqkv + 2*R_, bv, R_*4, hipMemcpyDeviceToDevice, stream);

  k_ln1_scatter<<<NROW_/4, 256, 0, stream>>>(x, ln1w, ln1b, uniqf);
  k_cvt<<<(BMR_*R_ + 255)/256, 256, 0, stream>>>(uniqf, uniqb, BMR_*R_);

  dim3 tb(32, 8);
  k_tcvt<<<dim3(R_/32, R_/32), tb, 0, stream>>>(wq, wqkvt, R_, R_);
  k_tcvt<<<dim3(R_/32, R_/32), tb, 0, stream>>>(wk, wqkvt + (size_t)R_*R_, R_, R_);
  k_tcvt<<<dim3(R_/32, R_/32), tb, 0, stream>>>(wvv, wqkvt + (size_t)2*R_*R_, R_, R_);
  k_tcvt<<<dim3(R_/32, R_/32), tb, 0, stream>>>(wo, wot, R_, R_);
  k_tcvt<<<dim3(HID_/32, NE_/32), tb, 0, stream>>>(w1, w1t, NE_, HID_);
  k_tcvt<<<dim3(NE_/32, HID_/32), tb, 0, stream>>>(w2, w2t, HID_, NE_);

  // merged QKV: N = 1152
  k_gemm<5><<<dim3(86, 9), 256, 0, stream>>>(uniqb, wqkvt, bqkv, qb, nullptr,
                                             kb, vtb, BMR_, 3*R_, R_);

  k_attn<<<dim3(22, 48), 256, 0, stream>>>(qb, kb, vtb, ob);

  k_gemm<0><<<dim3(86, 3), 256, 0, stream>>>(ob, wot, bo, attn_o, nullptr,
                                             nullptr, nullptr, BMR_, R_, R_);

  k_scatter_ln2<<<NROW_/4, 256, 0, stream>>>(x, attn_o, ln2w, ln2b, b2, out, flatb);

  // MLP up-proj: 8192x9216 = flatb(8192x2304) @ w1t^T, gelu -> bf16
  k_gemm8<1><<<dim3(32, 36), 512, 0, stream>>>(flatb, w1t, b1, h1b,
                                               8192, HID_, NE_, NE_);
  // MLP down-proj: split-K=2, fp32 atomicAdd onto out (= xres + b2)
  k_gemm8<3><<<dim3(32, 9, 2), 512, 0, stream>>>(h1b, w2t, nullptr, out,
                                                 8192, NE_, HID_, HID_/2);
}

// Round 5
// 1420.295 us; speedup vs baseline: 1.0233x; 1.0233x over previous
//
#include <hip/hip_runtime.h>
#include <cstddef>

#define B_    8
#define H_    32
#define W_    32
#define L_    6
#define R_    384
#define NH_   6
#define DH_   64
#define M_    1365
#define MPAD_ 1408
#define NE_   2304
#define HID_  9216
#define NROW_ 49152   // B*H*W*L
#define BMR_  10920   // B*M

typedef __bf16 bf16x8 __attribute__((ext_vector_type(8)));
typedef float  f32x4  __attribute__((ext_vector_type(4)));
typedef unsigned short us;

__device__ __forceinline__ unsigned short f2b(float f){
  unsigned u = __float_as_uint(f);
  u = (u + 0x7FFFu + ((u >> 16) & 1u)) >> 16;
  return (unsigned short)u;
}

__device__ __forceinline__ void gload16(const unsigned short* g, unsigned short* l){
  __builtin_amdgcn_global_load_lds(
      (const __attribute__((address_space(1))) unsigned int*)g,
      (__attribute__((address_space(3))) unsigned int*)l,
      16, 0, 0);
}

__device__ __forceinline__ float wsum(float s){
  #pragma unroll
  for (int o = 32; o > 0; o >>= 1) s += __shfl_xor(s, o, 64);
  return s;
}

__device__ __forceinline__ float rmax16(float v){
  v = fmaxf(v, __shfl_xor(v, 1, 64));
  v = fmaxf(v, __shfl_xor(v, 2, 64));
  v = fmaxf(v, __shfl_xor(v, 4, 64));
  v = fmaxf(v, __shfl_xor(v, 8, 64));
  return v;
}
__device__ __forceinline__ float rsum16(float v){
  v += __shfl_xor(v, 1, 64);
  v += __shfl_xor(v, 2, 64);
  v += __shfl_xor(v, 4, 64);
  v += __shfl_xor(v, 8, 64);
  return v;
}

// gelu(tanh approx) == x * sigmoid(1.5957691216*(x + 0.044715*x^3)) exactly.
__device__ __forceinline__ float gelu_fast(float x){
  float t = fmaf(0.07135482f * x, x * x, 1.5957691216f * x);
  return x / (1.0f + __expf(-t));
}

// ---------------- LN1 + scaled atomic scatter into uniq (B,M,R) ----------------
__global__ __launch_bounds__(256) void k_ln1_scatter(
    const float* __restrict__ x, const float* __restrict__ lw,
    const float* __restrict__ lb, float* __restrict__ uniq){
  int row  = blockIdx.x * 4 + (threadIdx.x >> 6);
  int lane = threadIdx.x & 63;
  int l  = row % 6;
  int hw = (row / 6) & 1023;
  int b  = row / 6144;
  int h = hw >> 5, w = hw & 31;
  const float* xr = x + (size_t)row * R_;
  float v[6]; float s = 0.f;
  #pragma unroll
  for (int i = 0; i < 6; i++){ v[i] = xr[lane + i*64]; s += v[i]; }
  s = wsum(s);
  float mu = s * (1.f/384.f);
  float qq = 0.f;
  #pragma unroll
  for (int i = 0; i < 6; i++){ float d = v[i]-mu; qq += d*d; }
  qq = wsum(qq);
  float rs = rsqrtf(qq * (1.f/384.f) + 1e-5f);
  int off = (4096 - (4096 >> (2*l))) / 3;
  int id  = off + (h >> l) * (32 >> l) + (w >> l);
  float invc = 1.f / (float)(1 << (2*l));
  float* ur = uniq + ((size_t)b * M_ + id) * R_;
  #pragma unroll
  for (int i = 0; i < 6; i++){
    int r = lane + i*64;
    float ln = (v[i]-mu)*rs*lw[r] + lb[r];
    atomicAdd(&ur[r], ln * invc);
  }
}

// ---------------- fp32 -> bf16 convert ----------------
__global__ void k_cvt(const float* __restrict__ src, unsigned short* __restrict__ dst, int n){
  int i = blockIdx.x * 256 + threadIdx.x;
  if (i < n) dst[i] = f2b(src[i]);
}

// ---------------- transpose + convert: src K x N fp32 -> dst N x K bf16 ----------------
__global__ void k_tcvt(const float* __restrict__ src, unsigned short* __restrict__ dst,
                       int K, int N){
  __shared__ float t[32][33];
  int n0 = blockIdx.x * 32, k0 = blockIdx.y * 32;
  int tx = threadIdx.x, ty = threadIdx.y;
  #pragma unroll
  for (int i = 0; i < 4; i++)
    t[ty + i*8][tx] = src[(size_t)(k0 + ty + i*8) * N + n0 + tx];
  __syncthreads();
  #pragma unroll
  for (int i = 0; i < 4; i++)
    dst[(size_t)(n0 + ty + i*8) * K + k0 + tx] = f2b(t[tx][ty + i*8]);
}

// ---------------- bf16 MFMA GEMM (128x128 tile, 2-phase) ----------------
// Kept for the small GEMMs (QKV EPI=5, attn-out EPI=0) where M/N aren't %256.
template<int EPI>
__global__ __launch_bounds__(256) void k_gemm(
    const unsigned short* __restrict__ A,   // M x K bf16
    const unsigned short* __restrict__ Bt,  // N x K bf16
    const float* __restrict__ bias,         // N
    void* __restrict__ Cout,
    const float* __restrict__ res,
    void* __restrict__ aux1, void* __restrict__ aux2,
    int Mtot, int N, int K){
  __shared__ unsigned short As[128*64];
  __shared__ unsigned short Bs[128*64];
  int m0 = blockIdx.x * 128, n0 = blockIdx.y * 128;
  int tid  = threadIdx.x;
  int wv   = tid >> 6, lane = tid & 63;
  int quad = lane >> 4, l16 = lane & 15;
  int wm = (wv >> 1) * 64, wn = (wv & 1) * 64;
  int lr = lane >> 3;          // row within 8-row chunk
  int lc = (lane & 7) * 8;     // short col within 64-col row
  f32x4 acc[4][4];
  #pragma unroll
  for (int a = 0; a < 4; a++)
    #pragma unroll
    for (int bidx = 0; bidx < 4; bidx++) acc[a][bidx] = 0.f;

  for (int k0 = 0; k0 < K; k0 += 64){
    #pragma unroll
    for (int j = 0; j < 4; j++){
      int c = wv*4 + j;            // chunk 0..15, 8 rows each
      int rowa = c*8 + lr;
      int gm = m0 + rowa; if (gm >= Mtot) gm = Mtot - 1;
      gload16(A + (size_t)gm * K + k0 + lc, &As[c*512]);
      int gn = n0 + rowa;          // N multiple of 128
      gload16(Bt + (size_t)gn * K + k0 + lc, &Bs[c*512]);
    }
    asm volatile("s_waitcnt vmcnt(0)" ::: "memory");
    __syncthreads();
    #pragma unroll
    for (int ko = 0; ko < 2; ko++){
      bf16x8 af[4], bfr[4];
      #pragma unroll
      for (int t = 0; t < 4; t++){
        af[t]  = *(const bf16x8*)(&As[(wm + t*16 + l16)*64 + ko*32 + quad*8]);
        bfr[t] = *(const bf16x8*)(&Bs[(wn + t*16 + l16)*64 + ko*32 + quad*8]);
      }
      #pragma unroll
      for (int mt = 0; mt < 4; mt++)
        #pragma unroll
        for (int nt = 0; nt < 4; nt++)
          acc[mt][nt] = __builtin_amdgcn_mfma_f32_16x16x32_bf16(
              af[mt], bfr[nt], acc[mt][nt], 0, 0, 0);
    }
    __syncthreads();
  }
  #pragma unroll
  for (int mt = 0; mt < 4; mt++){
    #pragma unroll
    for (int i = 0; i < 4; i++){
      int row = m0 + wm + mt*16 + quad*4 + i;
      if (row >= Mtot) continue;
      #pragma unroll
      for (int nt = 0; nt < 4; nt++){
        int col = n0 + wn + nt*16 + l16;
        size_t idx = (size_t)row * N + col;
        float vv = acc[mt][nt][i] + bias[col];
        if (EPI == 5){
          int bb = row / M_;
          int mm = row - bb * M_;
          if (col < 384){
            ((unsigned short*)Cout)[(size_t)row * R_ + col] = f2b(vv);
          } else if (col < 768){
            ((unsigned short*)aux1)[(size_t)row * R_ + col - 384] = f2b(vv);
          } else {
            int c2 = col - 768;
            int hh = c2 >> 6, dd = c2 & 63;
            ((unsigned short*)aux2)[(((size_t)(bb*NH_ + hh))*DH_ + dd)*MPAD_ + mm] = f2b(vv);
          }
        } else {
          ((float*)Cout)[idx] = vv;
        }
      }
    }
  }
}

// ========== 256x256 cross-phase counted-lgkm pipelined bf16 GEMM ==========
// New mechanism vs r1-r4 (which all lgkm(0)-drained before every MFMA cluster):
// phase P+1's A-frag ds_reads are issued BEFORE phase P's MFMA cluster and wait
// with COUNTED lgkmcnt(4) (retire P's reads, leave P+1's in flight) -> each
// phase's LDS drain hides under the previous phase's MFMA. Only the tile-
// initial 12-read drain is exposed. 2 barriers/tile (B-restage + tile bound).
// Issue groups are SB0-pinned so the counted-wait retire-sets are exact
// (rule #18: SB0 after every counted wait, before each MFMA cluster).
// vmcnt(4) once/tile keeps B(t+2) in flight. T2 granule swizzle unchanged.
// 8 waves (2Mx4N), per-wave C = 128x64. LDS 128 KiB -> 1 block/CU.
// REQUIRES: Mtot%256==0, N%256==0, kLen%64==0, (kLen/64)%2==0.
// EPI 1: bias+gelu -> bf16.  EPI 3: fp32 atomicAdd into pre-initialized Cout.

__device__ __forceinline__ void stage_half(const unsigned short* __restrict__ g,
                                           unsigned short* l, int K){
  int tid = threadIdx.x;
  int w  = tid >> 6;                  // wave 0..7 -> rows w*16..w*16+15
  int ln = tid & 63;
  int rw = ln >> 3;                   // row within 8-row chunk (== row&7)
  int cs = ((ln & 7) ^ rw) * 8;       // swizzled short-col (pre-swizzled source)
  gload16(g + (size_t)(w*16 + rw)     * K + cs, l + (w*16)*64);
  gload16(g + (size_t)(w*16 + 8 + rw) * K + cs, l + (w*16 + 8)*64);
}

__device__ __forceinline__ bf16x8 ldsfrag(const unsigned short* base, int row, int ko, int quad){
  int g = ((ko << 2) + quad) ^ (row & 7);   // un-swizzle: slot g holds granule g^(row&7)
  return *(const bf16x8*)(base + row*64 + g*8);
}

#define SB0()  __builtin_amdgcn_sched_barrier(0)
#define MFMA16(A8, B8, C4) __builtin_amdgcn_mfma_f32_16x16x32_bf16(A8, B8, C4, 0, 0, 0)

// 16-MFMA cluster for acc rows I0, I0+1 from frag pair AF (AF[r][ko]).
#define CL2(I0, AF)                                                              \
  { __builtin_amdgcn_s_setprio(1);                                              \
    _Pragma("unroll")                                                            \
    for (int nt = 0; nt < 4; nt++)                                               \
      acc[I0][nt]   = MFMA16(AF[0][0], bfr[nt][0], acc[I0][nt]);                 \
    _Pragma("unroll")                                                            \
    for (int nt = 0; nt < 4; nt++)                                               \
      acc[I0+1][nt] = MFMA16(AF[1][0], bfr[nt][0], acc[I0+1][nt]);               \
    _Pragma("unroll")                                                            \
    for (int nt = 0; nt < 4; nt++)                                               \
      acc[I0][nt]   = MFMA16(AF[0][1], bfr[nt][1], acc[I0][nt]);                 \
    _Pragma("unroll")                                                            \
    for (int nt = 0; nt < 4; nt++)                                               \
      acc[I0+1][nt] = MFMA16(AF[1][1], bfr[nt][1], acc[I0+1][nt]);               \
    __builtin_amdgcn_s_setprio(0); }

#define RDA(DST, RBASE)                                                          \
  _Pragma("unroll")                                                              \
  for (int r = 0; r < 2; r++){                                                   \
    DST[r][0] = ldsfrag(curA, wr*128 + ((RBASE)+r)*16 + l16, 0, quad);           \
    DST[r][1] = ldsfrag(curA, wr*128 + ((RBASE)+r)*16 + l16, 1, quad);           \
  }

#define KTILE(CURBUF)                                                            \
  { us* curA = &lds8[CURBUF][0];                                                 \
    us* curB = curA + 16384;                                                     \
    us* nxtA = &lds8[(CURBUF) ^ 1][0];                                           \
    bool st1 = (t + 1 < NT), st2 = (t + 2 < NT);                                 \
    const us* An = Ab + (size_t)(t + 1) * 64;                                    \
    const us* Bn = Bb + (size_t)(t + 2) * 64;                                    \
    bf16x8 bfr[4][2], a0[2][2], a1[2][2];                                        \
    /* pinned issue order: B x8 | a0 x4 | a1 x4  (lgkm retire-sets depend) */    \
    _Pragma("unroll")                                                            \
    for (int nt = 0; nt < 4; nt++){                                              \
      bfr[nt][0] = ldsfrag(curB, wc*64 + nt*16 + l16, 0, quad);                  \
      bfr[nt][1] = ldsfrag(curB, wc*64 + nt*16 + l16, 1, quad);                  \
    }                                                                            \
    SB0();                                                                       \
    RDA(a0, 0); SB0();                                                           \
    RDA(a1, 2); SB0();                                                           \
    if (st1){ stage_half(An,          nxtA,        Kfull);                       \
              stage_half(An + 128*KS, nxtA + 8192, Kfull); }                     \
    SB0();                                                                       \
    asm volatile("s_waitcnt lgkmcnt(4)" ::: "memory");  /* B,a0 done; a1 fly */  \
    SB0();                                                                       \
    CL2(0, a0);                                                                  \
    SB0();                                                                       \
    RDA(a0, 4); SB0();                       /* rows 4,5 in flight */            \
    asm volatile("s_waitcnt lgkmcnt(4)" ::: "memory");  /* a1 done */            \
    SB0();                                                                       \
    CL2(2, a1);                                                                  \
    SB0();                                                                       \
    __builtin_amdgcn_s_barrier();            /* all waves consumed B */          \
    SB0();                                                                       \
    if (st2){ stage_half(Bn,          curB,        Kfull);                       \
              stage_half(Bn + 128*KS, curB + 8192, Kfull); }                     \
    SB0();                                                                       \
    RDA(a1, 6); SB0();                       /* rows 6,7 in flight */            \
    asm volatile("s_waitcnt lgkmcnt(4)" ::: "memory");  /* rows 4,5 done */      \
    SB0();                                                                       \
    CL2(4, a0);                                                                  \
    SB0();                                                                       \
    asm volatile("s_waitcnt lgkmcnt(0)" ::: "memory");  /* rows 6,7 done */      \
    SB0();                                                                       \
    CL2(6, a1);                                                                  \
    SB0();                                                                       \
    if (st1){                                                                    \
      if (st2) asm volatile("s_waitcnt vmcnt(4)" ::: "memory");                  \
      else     asm volatile("s_waitcnt vmcnt(0)" ::: "memory");                  \
    }                                                                            \
    __builtin_amdgcn_s_barrier();                                                \
    SB0();                                                                       \
    ++t; }

template<int EPI>
__global__ __launch_bounds__(512, 2) void k_gemm8(
    const unsigned short* __restrict__ A,   // Mtot x Kfull bf16
    const unsigned short* __restrict__ Bt,  // N x Kfull bf16
    const float* __restrict__ bias,
    void* __restrict__ Cout,
    int Mtot, int N, int Kfull, int kLen){
  __shared__ unsigned short lds8[2][32768];  // [buf][A 256x64 | B 256x64]

  int m0 = blockIdx.x * 256, n0 = blockIdx.y * 256;
  int k0 = blockIdx.z * kLen;
  int NT = kLen >> 6;                        // must be even
  const size_t KS = (size_t)Kfull;
  const us* Ab = A  + (size_t)m0 * KS + k0;
  const us* Bb = Bt + (size_t)n0 * KS + k0;
  int tid = threadIdx.x, wv = tid >> 6, lane = tid & 63;
  int quad = lane >> 4, l16 = lane & 15;
  int wr = wv >> 2, wc = wv & 3;       // 2M x 4N wave grid

  f32x4 acc[8][4];
  #pragma unroll
  for (int a = 0; a < 8; a++)
    #pragma unroll
    for (int b = 0; b < 4; b++) acc[a][b] = 0.f;

  // ---- prologue: tile0 all 4 halves into buf0; tile1 B-halves into buf1 ----
  stage_half(Bb,               &lds8[0][16384],        Kfull);  // H(0, B0)
  stage_half(Bb + 128*KS,      &lds8[0][16384 + 8192], Kfull);  // H(0, B1)
  stage_half(Ab,               &lds8[0][0],            Kfull);  // H(0, A0)
  stage_half(Ab + 128*KS,      &lds8[0][8192],         Kfull);  // H(0, A1)
  if (NT > 1){
    stage_half(Bb + 64,             &lds8[1][16384],        Kfull);  // H(1, B0)
    stage_half(Bb + 128*KS + 64,    &lds8[1][16384 + 8192], Kfull);  // H(1, B1)
    asm volatile("s_waitcnt vmcnt(4)" ::: "memory");
  } else {
    asm volatile("s_waitcnt vmcnt(0)" ::: "memory");
  }
  __builtin_amdgcn_s_barrier();
  SB0();

  int t = 0;
  while (t < NT){
    KTILE(0);
    KTILE(1);
  }

  // ---- epilogue ----
  #pragma unroll
  for (int mt = 0; mt < 8; mt++){
    #pragma unroll
    for (int i = 0; i < 4; i++){
      int row = m0 + wr*128 + mt*16 + quad*4 + i;
      #pragma unroll
      for (int nt = 0; nt < 4; nt++){
        int col = n0 + wc*64 + nt*16 + l16;
        size_t idx = (size_t)row * N + col;
        float vv = acc[mt][nt][i];
        if (EPI == 1){
          ((unsigned short*)Cout)[idx] = f2b(gelu_fast(vv + bias[col]));
        } else {
          atomicAdd(&((float*)Cout)[idx], vv);
        }
      }
    }
  }
}

// ---------------- bf16 MFMA flash attention over M=1365 nodes ----------------
__global__ __launch_bounds__(256) void k_attn(
    const unsigned short* __restrict__ qb, const unsigned short* __restrict__ kb,
    const unsigned short* __restrict__ vtb, unsigned short* __restrict__ ob){
  __shared__ unsigned short Ks[64][64];
  __shared__ unsigned short Vt[64][64];
  __shared__ unsigned short Ps[4][16][64];
  int qt = blockIdx.x, bh = blockIdx.y;
  int b = bh / NH_, h = bh % NH_;
  int tid = threadIdx.x, wv = tid >> 6, lane = tid & 63;
  int quad = lane >> 4, l16 = lane & 15;

  int qm = qt*64 + wv*16 + l16;
  const unsigned short* qrow = qb + (size_t)(b*M_ + qm)*R_ + h*DH_;
  bf16x8 aq0 = *(const bf16x8*)(qrow + quad*8);
  bf16x8 aq1 = *(const bf16x8*)(qrow + 32 + quad*8);

  f32x4 oacc[4];
  #pragma unroll
  for (int db = 0; db < 4; db++) oacc[db] = 0.f;
  float mi[4], li[4];
  #pragma unroll
  for (int i = 0; i < 4; i++){ mi[i] = -1e30f; li[i] = 0.f; }

  for (int kt = 0; kt < 22; kt++){
    #pragma unroll
    for (int i = 0; i < 2; i++){
      int c = tid + i*256;
      int rowa = c >> 3, colc = (c & 7) * 8;
      *(uint4*)(&Ks[rowa][colc]) =
        *(const uint4*)(kb + (size_t)(b*M_ + kt*64 + rowa)*R_ + h*DH_ + colc);
      *(uint4*)(&Vt[rowa][colc]) =
        *(const uint4*)(vtb + ((size_t)bh*DH_ + rowa)*MPAD_ + kt*64 + colc);
    }
    __syncthreads();

    f32x4 s[4];
    #pragma unroll
    for (int nb = 0; nb < 4; nb++){
      s[nb] = 0.f;
      bf16x8 bk0 = *(const bf16x8*)(&Ks[nb*16 + l16][quad*8]);
      bf16x8 bk1 = *(const bf16x8*)(&Ks[nb*16 + l16][32 + quad*8]);
      s[nb] = __builtin_amdgcn_mfma_f32_16x16x32_bf16(aq0, bk0, s[nb], 0, 0, 0);
      s[nb] = __builtin_amdgcn_mfma_f32_16x16x32_bf16(aq1, bk1, s[nb], 0, 0, 0);
    }

    #pragma unroll
    for (int i = 0; i < 4; i++){
      float val[4];
      float mx = -1e30f;
      #pragma unroll
      for (int nb = 0; nb < 4; nb++){
        int gc = kt*64 + nb*16 + l16;
        val[nb] = (gc < M_) ? s[nb][i] * 0.125f : -1e30f;
        mx = fmaxf(mx, val[nb]);
      }
      mx = rmax16(mx);
      float mnew = fmaxf(mi[i], mx);
      float alpha = __expf(mi[i] - mnew);
      float rs = 0.f;
      #pragma unroll
      for (int nb = 0; nb < 4; nb++){
        float p = __expf(val[nb] - mnew);
        rs += p;
        Ps[wv][quad*4 + i][nb*16 + l16] = f2b(p);
      }
      rs = rsum16(rs);
      li[i] = li[i]*alpha + rs;
      mi[i] = mnew;
      #pragma unroll
      for (int db = 0; db < 4; db++) oacc[db][i] *= alpha;
    }

    #pragma unroll
    for (int ko = 0; ko < 2; ko++){
      bf16x8 ap = *(const bf16x8*)(&Ps[wv][l16][ko*32 + quad*8]);
      #pragma unroll
      for (int db = 0; db < 4; db++){
        bf16x8 bv = *(const bf16x8*)(&Vt[db*16 + l16][ko*32 + quad*8]);
        oacc[db] = __builtin_amdgcn_mfma_f32_16x16x32_bf16(ap, bv, oacc[db], 0, 0, 0);
      }
    }
    __syncthreads();
  }

  #pragma unroll
  for (int i = 0; i < 4; i++){
    int gm = qt*64 + wv*16 + quad*4 + i;
    if (gm < M_){
      float il = 1.f / li[i];
      #pragma unroll
      for (int db = 0; db < 4; db++)
        ob[(size_t)(b*M_ + gm)*R_ + h*DH_ + db*16 + l16] = f2b(oacc[db][i] * il);
    }
  }
}

// ---- scatter attn_out + residual -> xres; out = xres + b2 (MLP2 base); LN2 -> flat bf16 ----
__global__ __launch_bounds__(256) void k_scatter_ln2(
    const float* __restrict__ x, const float* __restrict__ attn,
    const float* __restrict__ lw, const float* __restrict__ lb,
    const float* __restrict__ b2,
    float* __restrict__ xres, unsigned short* __restrict__ flatb){
  int row  = blockIdx.x * 4 + (threadIdx.x >> 6);
  int lane = threadIdx.x & 63;
  int l  = row % 6;
  int hw = (row / 6) & 1023;
  int b  = row / 6144;
  int h = hw >> 5, w = hw & 31;
  int off = (4096 - (4096 >> (2*l))) / 3;
  int id  = off + (h >> l) * (32 >> l) + (w >> l);
  const float* ar = attn + ((size_t)b * M_ + id) * R_;
  const float* xr = x + (size_t)row * R_;
  float* orow = xres + (size_t)row * R_;
  float vv[6]; float s = 0.f;
  #pragma unroll
  for (int i = 0; i < 6; i++){
    int r = lane + i*64;
    float t = xr[r] + ar[r];
    vv[i] = t; s += t;
    orow[r] = t + b2[l*R_ + r];     // pre-fold bias: MLP2 partials atomicAdd onto this
  }
  s = wsum(s);
  float mu = s * (1.f/384.f);
  float qq = 0.f;
  #pragma unroll
  for (int i = 0; i < 6; i++){ float d = vv[i]-mu; qq += d*d; }
  qq = wsum(qq);
  float rs = rsqrtf(qq * (1.f/384.f) + 1e-5f);
  unsigned short* fr = flatb + (size_t)row * R_;
  #pragma unroll
  for (int i = 0; i < 6; i++){
    int r = lane + i*64;
    fr[r] = f2b((vv[i]-mu)*rs*lw[r] + lb[r]);
  }
}

extern "C" void kernel_launch(void* const* d_in, const int* in_sizes, int n_in,
                              void* d_out, int out_size, void* d_ws, size_t ws_size,
                              hipStream_t stream){
  const float* x    = (const float*)d_in[0];
  const float* ln1w = (const float*)d_in[1];
  const float* ln1b = (const float*)d_in[2];
  const float* ln2w = (const float*)d_in[3];
  const float* ln2b = (const float*)d_in[4];
  const float* wq   = (const float*)d_in[5];
  const float* bq   = (const float*)d_in[6];
  const float* wk   = (const float*)d_in[7];
  const float* bk   = (const float*)d_in[8];
  const float* wvv  = (const float*)d_in[9];
  const float* bv   = (const float*)d_in[10];
  const float* wo   = (const float*)d_in[11];
  const float* bo   = (const float*)d_in[12];
  const float* w1   = (const float*)d_in[13];
  const float* b1   = (const float*)d_in[14];
  const float* w2   = (const float*)d_in[15];
  const float* b2   = (const float*)d_in[16];
  float* out = (float*)d_out;

  // ---- workspace layout ----
  char* ws = (char*)d_ws;
  unsigned short* h1b = (unsigned short*)ws;                     // 8192*9216 bf16 (reuses region A)
  unsigned short* qb  = (unsigned short*)ws;
  unsigned short* kb  = qb + (size_t)BMR_ * R_;
  unsigned short* vtb = kb + (size_t)BMR_ * R_;
  unsigned short* ob  = vtb + (size_t)B_ * NH_ * DH_ * MPAD_;
  float* attn_o = (float*)(ob + (size_t)BMR_ * R_);
  size_t regA = ((size_t)8192 * HID_ * 2 + 255) & ~(size_t)255;
  char* p = ws + regA;
  float* uniqf = (float*)p;                   p += (size_t)BMR_ * R_ * 4;
  unsigned short* uniqb = (unsigned short*)p; p += (size_t)BMR_ * R_ * 2;
  unsigned short* wqkvt = (unsigned short*)p; p += (size_t)3 * R_ * R_ * 2;
  unsigned short* wot = (unsigned short*)p;   p += (size_t)R_ * R_ * 2;
  unsigned short* w1t = (unsigned short*)p;   p += (size_t)NE_ * HID_ * 2;
  unsigned short* w2t = (unsigned short*)p;   p += (size_t)NE_ * HID_ * 2;
  unsigned short* flatb = (unsigned short*)p; p += (size_t)NROW_ * R_ * 2;
  float* bqkv = (float*)p;                    p += (size_t)3 * R_ * 4;

  hipMemsetAsync(uniqf, 0, (size_t)BMR_ * R_ * 4, stream);
  hipMemsetAsync(vtb, 0, (size_t)B_ * NH_ * DH_ * MPAD_ * 2, stream);
  hipMemcpyAsync(bqkv,        bq, R_*4, hipMemcpyDeviceToDevice, stream);
  hipMemcpyAsync(bqkv + R_,   bk, R_*4, hipMemcpyDeviceToDevice, stream);
  hipMemcpyAsync(bqkv + 2*R_, bv, R_*4, hipMemcpyDeviceToDevice, stream);

  k_ln1_scatter<<<NROW_/4, 256, 0, stream>>>(x, ln1w, ln1b, uniqf);
  k_cvt<<<(BMR_*R_ + 255)/256, 256, 0, stream>>>(uniqf, uniqb, BMR_*R_);

  dim3 tb(32, 8);
  k_tcvt<<<dim3(R_/32, R_/32), tb, 0, stream>>>(wq, wqkvt, R_, R_);
  k_tcvt<<<dim3(R_/32, R_/32), tb, 0, stream>>>(wk, wqkvt + (size_t)R_*R_, R_, R_);
  k_tcvt<<<dim3(R_/32, R_/32), tb, 0, stream>>>(wvv, wqkvt + (size_t)2*R_*R_, R_, R_);
  k_tcvt<<<dim3(R_/32, R_/32), tb, 0, stream>>>(wo, wot, R_, R_);
  k_tcvt<<<dim3(HID_/32, NE_/32), tb, 0, stream>>>(w1, w1t, NE_, HID_);
  k_tcvt<<<dim3(NE_/32, HID_/32), tb, 0, stream>>>(w2, w2t, HID_, NE_);

  // merged QKV: N = 1152
  k_gemm<5><<<dim3(86, 9), 256, 0, stream>>>(uniqb, wqkvt, bqkv, qb, nullptr,
                                             kb, vtb, BMR_, 3*R_, R_);

  k_attn<<<dim3(22, 48), 256, 0, stream>>>(qb, kb, vtb, ob);

  k_gemm<0><<<dim3(86, 3), 256, 0, stream>>>(ob, wot, bo, attn_o, nullptr,
                                             nullptr, nullptr, BMR_, R_, R_);

  k_scatter_ln2<<<NROW_/4, 256, 0, stream>>>(x, attn_o, ln2w, ln2b, b2, out, flatb);

  // MLP up-proj: 8192x9216 = flatb(8192x2304) @ w1t^T, gelu -> bf16
  k_gemm8<1><<<dim3(32, 36), 512, 0, stream>>>(flatb, w1t, b1, h1b,
                                               8192, HID_, NE_, NE_);
  // MLP down-proj: split-K=2, fp32 atomicAdd onto out (= xres + b2)
  k_gemm8<3><<<dim3(32, 9, 2), 512, 0, stream>>>(h1b, w2t, nullptr, out,
                                                 8192, NE_, HID_, HID_/2);
}

// Round 7
// 1403.518 us; speedup vs baseline: 1.0355x; 1.0120x over previous
//
#include <hip/hip_runtime.h>
#include <cstddef>

#define B_    8
#define H_    32
#define W_    32
#define L_    6
#define R_    384
#define NH_   6
#define DH_   64
#define M_    1365
#define MPAD_ 1408
#define NE_   2304
#define HID_  9216
#define NROW_ 49152   // B*H*W*L
#define BMR_  10920   // B*M

typedef __bf16 bf16x8 __attribute__((ext_vector_type(8)));
typedef float  f32x4  __attribute__((ext_vector_type(4)));
typedef unsigned short us;

__device__ __forceinline__ unsigned short f2b(float f){
  unsigned u = __float_as_uint(f);
  u = (u + 0x7FFFu + ((u >> 16) & 1u)) >> 16;
  return (unsigned short)u;
}

__device__ __forceinline__ void gload16(const unsigned short* g, unsigned short* l){
  __builtin_amdgcn_global_load_lds(
      (const __attribute__((address_space(1))) unsigned int*)g,
      (__attribute__((address_space(3))) unsigned int*)l,
      16, 0, 0);
}

__device__ __forceinline__ float wsum(float s){
  #pragma unroll
  for (int o = 32; o > 0; o >>= 1) s += __shfl_xor(s, o, 64);
  return s;
}

__device__ __forceinline__ float rmax16(float v){
  v = fmaxf(v, __shfl_xor(v, 1, 64));
  v = fmaxf(v, __shfl_xor(v, 2, 64));
  v = fmaxf(v, __shfl_xor(v, 4, 64));
  v = fmaxf(v, __shfl_xor(v, 8, 64));
  return v;
}
__device__ __forceinline__ float rsum16(float v){
  v += __shfl_xor(v, 1, 64);
  v += __shfl_xor(v, 2, 64);
  v += __shfl_xor(v, 4, 64);
  v += __shfl_xor(v, 8, 64);
  return v;
}

// gelu(tanh approx) == x * sigmoid(1.5957691216*(x + 0.044715*x^3)) exactly.
__device__ __forceinline__ float gelu_fast(float x){
  float t = fmaf(0.07135482f * x, x * x, 1.5957691216f * x);
  return x / (1.0f + __expf(-t));
}

// ---------------- LN1 + scaled atomic scatter into uniq (B,M,R) ----------------
__global__ __launch_bounds__(256) void k_ln1_scatter(
    const float* __restrict__ x, const float* __restrict__ lw,
    const float* __restrict__ lb, float* __restrict__ uniq){
  int row  = blockIdx.x * 4 + (threadIdx.x >> 6);
  int lane = threadIdx.x & 63;
  int l  = row % 6;
  int hw = (row / 6) & 1023;
  int b  = row / 6144;
  int h = hw >> 5, w = hw & 31;
  const float* xr = x + (size_t)row * R_;
  float v[6]; float s = 0.f;
  #pragma unroll
  for (int i = 0; i < 6; i++){ v[i] = xr[lane + i*64]; s += v[i]; }
  s = wsum(s);
  float mu = s * (1.f/384.f);
  float qq = 0.f;
  #pragma unroll
  for (int i = 0; i < 6; i++){ float d = v[i]-mu; qq += d*d; }
  qq = wsum(qq);
  float rs = rsqrtf(qq * (1.f/384.f) + 1e-5f);
  int off = (4096 - (4096 >> (2*l))) / 3;
  int id  = off + (h >> l) * (32 >> l) + (w >> l);
  float invc = 1.f / (float)(1 << (2*l));
  float* ur = uniq + ((size_t)b * M_ + id) * R_;
  #pragma unroll
  for (int i = 0; i < 6; i++){
    int r = lane + i*64;
    float ln = (v[i]-mu)*rs*lw[r] + lb[r];
    atomicAdd(&ur[r], ln * invc);
  }
}

// ---------------- fp32 -> bf16 convert ----------------
__global__ void k_cvt(const float* __restrict__ src, unsigned short* __restrict__ dst, int n){
  int i = blockIdx.x * 256 + threadIdx.x;
  if (i < n) dst[i] = f2b(src[i]);
}

// ---------------- transpose + convert: src K x N fp32 -> dst N x K bf16 ----------------
__global__ void k_tcvt(const float* __restrict__ src, unsigned short* __restrict__ dst,
                       int K, int N){
  __shared__ float t[32][33];
  int n0 = blockIdx.x * 32, k0 = blockIdx.y * 32;
  int tx = threadIdx.x, ty = threadIdx.y;
  #pragma unroll
  for (int i = 0; i < 4; i++)
    t[ty + i*8][tx] = src[(size_t)(k0 + ty + i*8) * N + n0 + tx];
  __syncthreads();
  #pragma unroll
  for (int i = 0; i < 4; i++)
    dst[(size_t)(n0 + ty + i*8) * K + k0 + tx] = f2b(t[tx][ty + i*8]);
}

// ---------------- bf16 MFMA GEMM (128x128 tile, 2-phase) ----------------
// Kept for the small GEMMs (QKV EPI=5, attn-out EPI=0) where M/N aren't %256.
template<int EPI>
__global__ __launch_bounds__(256) void k_gemm(
    const unsigned short* __restrict__ A,   // M x K bf16
    const unsigned short* __restrict__ Bt,  // N x K bf16
    const float* __restrict__ bias,         // N
    void* __restrict__ Cout,
    const float* __restrict__ res,
    void* __restrict__ aux1, void* __restrict__ aux2,
    int Mtot, int N, int K){
  __shared__ unsigned short As[128*64];
  __shared__ unsigned short Bs[128*64];
  int m0 = blockIdx.x * 128, n0 = blockIdx.y * 128;
  int tid  = threadIdx.x;
  int wv   = tid >> 6, lane = tid & 63;
  int quad = lane >> 4, l16 = lane & 15;
  int wm = (wv >> 1) * 64, wn = (wv & 1) * 64;
  int lr = lane >> 3;          // row within 8-row chunk
  int lc = (lane & 7) * 8;     // short col within 64-col row
  f32x4 acc[4][4];
  #pragma unroll
  for (int a = 0; a < 4; a++)
    #pragma unroll
    for (int bidx = 0; bidx < 4; bidx++) acc[a][bidx] = 0.f;

  for (int k0 = 0; k0 < K; k0 += 64){
    #pragma unroll
    for (int j = 0; j < 4; j++){
      int c = wv*4 + j;            // chunk 0..15, 8 rows each
      int rowa = c*8 + lr;
      int gm = m0 + rowa; if (gm >= Mtot) gm = Mtot - 1;
      gload16(A + (size_t)gm * K + k0 + lc, &As[c*512]);
      int gn = n0 + rowa;          // N multiple of 128
      gload16(Bt + (size_t)gn * K + k0 + lc, &Bs[c*512]);
    }
    asm volatile("s_waitcnt vmcnt(0)" ::: "memory");
    __syncthreads();
    #pragma unroll
    for (int ko = 0; ko < 2; ko++){
      bf16x8 af[4], bfr[4];
      #pragma unroll
      for (int t = 0; t < 4; t++){
        af[t]  = *(const bf16x8*)(&As[(wm + t*16 + l16)*64 + ko*32 + quad*8]);
        bfr[t] = *(const bf16x8*)(&Bs[(wn + t*16 + l16)*64 + ko*32 + quad*8]);
      }
      #pragma unroll
      for (int mt = 0; mt < 4; mt++)
        #pragma unroll
        for (int nt = 0; nt < 4; nt++)
          acc[mt][nt] = __builtin_amdgcn_mfma_f32_16x16x32_bf16(
              af[mt], bfr[nt], acc[mt][nt], 0, 0, 0);
    }
    __syncthreads();
  }
  #pragma unroll
  for (int mt = 0; mt < 4; mt++){
    #pragma unroll
    for (int i = 0; i < 4; i++){
      int row = m0 + wm + mt*16 + quad*4 + i;
      if (row >= Mtot) continue;
      #pragma unroll
      for (int nt = 0; nt < 4; nt++){
        int col = n0 + wn + nt*16 + l16;
        size_t idx = (size_t)row * N + col;
        float vv = acc[mt][nt][i] + bias[col];
        if (EPI == 5){
          int bb = row / M_;
          int mm = row - bb * M_;
          if (col < 384){
            ((unsigned short*)Cout)[(size_t)row * R_ + col] = f2b(vv);
          } else if (col < 768){
            ((unsigned short*)aux1)[(size_t)row * R_ + col - 384] = f2b(vv);
          } else {
            int c2 = col - 768;
            int hh = c2 >> 6, dd = c2 & 63;
            ((unsigned short*)aux2)[(((size_t)(bb*NH_ + hh))*DH_ + dd)*MPAD_ + mm] = f2b(vv);
          }
        } else {
          ((float*)Cout)[idx] = vv;
        }
      }
    }
  }
}

// ========== 128x128 2-blocks/CU counted-vmcnt bf16 GEMM (occupancy pivot) ==========
// r1-r5 (256² tile, 128 KiB LDS, 1 block/CU) plateaued at 33% MfmaUtil across 4
// different K-loop schedules -> limiter is lack of co-residency: when the single
// block serializes (LDS drain/barrier), the CU idles. This config: 64 KiB LDS ->
// 2 blocks/CU; block A's drains overlap block B's MFMAs (m114 mechanism; m103:
// 128²=912 TF > 256²=792 at the same 2-barrier structure). Keeps T2 granule
// swizzle (0 conflicts) + counted vmcnt(8) double-buffer staging (in steady
// state never drains to 0). 4 waves (2Mx2N), per-wave C = 64x64.
// In-place restage hazard: all waves bulk-read their 16 frags -> lgkm(0) ->
// barrier -> stage T(t+2) into current buf; DMA lands before the re-read two
// iters later (end-of-iter t+1 vmcnt(8) + barrier orders it).
// REQUIRES: Mtot%128==0, N%128==0, kLen%64==0, (kLen/64)%2==0.
// EPI 1: bias+gelu -> bf16.  EPI 3: fp32 atomicAdd into pre-initialized Cout.

__device__ __forceinline__ void stage_tileO(const unsigned short* __restrict__ g,
                                            unsigned short* l, int K){
  int tid = threadIdx.x;
  int w  = tid >> 6;                  // wave 0..3 -> rows w*32..w*32+31
  int ln = tid & 63;
  int rw = ln >> 3;                   // row within 8-row chunk (== row&7)
  int cs = ((ln & 7) ^ rw) * 8;       // swizzled short-col (pre-swizzled source)
  #pragma unroll
  for (int k = 0; k < 4; k++)
    gload16(g + (size_t)(w*32 + k*8 + rw) * K + cs, l + (w*32 + k*8)*64);
}

__device__ __forceinline__ bf16x8 ldsfrag(const unsigned short* base, int row, int ko, int quad){
  int g = ((ko << 2) + quad) ^ (row & 7);   // un-swizzle: slot g holds granule g^(row&7)
  return *(const bf16x8*)(base + row*64 + g*8);
}

#define SB0()  __builtin_amdgcn_sched_barrier(0)
#define MFMA16(A8, B8, C4) __builtin_amdgcn_mfma_f32_16x16x32_bf16(A8, B8, C4, 0, 0, 0)

#define KTILEO(CURBUF)                                                           \
  { const us* curA = &ldsO[CURBUF][0];                                           \
    const us* curB = curA + 8192;                                                \
    bool st2 = (t + 2 < NT), st1 = (t + 1 < NT);                                 \
    bf16x8 af[4][2], bfr[4][2];                                                  \
    _Pragma("unroll")                                                            \
    for (int mt = 0; mt < 4; mt++){                                              \
      af[mt][0] = ldsfrag(curA, wr*64 + mt*16 + l16, 0, quad);                   \
      af[mt][1] = ldsfrag(curA, wr*64 + mt*16 + l16, 1, quad);                   \
    }                                                                            \
    _Pragma("unroll")                                                            \
    for (int nt = 0; nt < 4; nt++){                                              \
      bfr[nt][0] = ldsfrag(curB, wc*64 + nt*16 + l16, 0, quad);                  \
      bfr[nt][1] = ldsfrag(curB, wc*64 + nt*16 + l16, 1, quad);                  \
    }                                                                            \
    asm volatile("s_waitcnt lgkmcnt(0)" ::: "memory");                           \
    SB0();                                                                       \
    __builtin_amdgcn_s_barrier();   /* all waves hold frags in regs */           \
    SB0();                                                                       \
    if (st2){                                                                    \
      stage_tileO(Ab + (size_t)(t + 2) * 64, &ldsO[CURBUF][0],    Kfull);        \
      stage_tileO(Bb + (size_t)(t + 2) * 64, &ldsO[CURBUF][8192], Kfull);        \
    }                                                                            \
    SB0();                                                                       \
    __builtin_amdgcn_s_setprio(1);                                               \
    _Pragma("unroll")                                                            \
    for (int ko = 0; ko < 2; ko++)                                               \
      _Pragma("unroll")                                                          \
      for (int mt = 0; mt < 4; mt++)                                             \
        _Pragma("unroll")                                                        \
        for (int nt = 0; nt < 4; nt++)                                           \
          acc[mt][nt] = MFMA16(af[mt][ko], bfr[nt][ko], acc[mt][nt]);            \
    __builtin_amdgcn_s_setprio(0);                                               \
    SB0();                                                                       \
    if (st2)      asm volatile("s_waitcnt vmcnt(8)" ::: "memory");               \
    else if (st1) asm volatile("s_waitcnt vmcnt(0)" ::: "memory");               \
    __builtin_amdgcn_s_barrier();                                                \
    SB0();                                                                       \
    ++t; }

template<int EPI>
__global__ __launch_bounds__(256, 2) void k_gemmO(
    const unsigned short* __restrict__ A,   // Mtot x Kfull bf16
    const unsigned short* __restrict__ Bt,  // N x Kfull bf16
    const float* __restrict__ bias,
    void* __restrict__ Cout,
    int Mtot, int N, int Kfull, int kLen){
  __shared__ unsigned short ldsO[2][16384];  // [buf][A 128x64 | B 128x64] = 64 KiB

  int m0 = blockIdx.x * 128, n0 = blockIdx.y * 128;
  int k0 = blockIdx.z * kLen;
  int NT = kLen >> 6;                        // must be even
  const us* Ab = A  + (size_t)m0 * (size_t)Kfull + k0;
  const us* Bb = Bt + (size_t)n0 * (size_t)Kfull + k0;
  int tid = threadIdx.x, wv = tid >> 6, lane = tid & 63;
  int quad = lane >> 4, l16 = lane & 15;
  int wr = wv >> 1, wc = wv & 1;       // 2M x 2N wave grid

  f32x4 acc[4][4];
  #pragma unroll
  for (int a = 0; a < 4; a++)
    #pragma unroll
    for (int b = 0; b < 4; b++) acc[a][b] = 0.f;

  // ---- prologue: tile0 -> buf0; tile1 -> buf1; wait tile0 (8 left in flight) ----
  stage_tileO(Ab, &ldsO[0][0],    Kfull);
  stage_tileO(Bb, &ldsO[0][8192], Kfull);
  if (NT > 1){
    stage_tileO(Ab + 64, &ldsO[1][0],    Kfull);
    stage_tileO(Bb + 64, &ldsO[1][8192], Kfull);
    asm volatile("s_waitcnt vmcnt(8)" ::: "memory");
  } else {
    asm volatile("s_waitcnt vmcnt(0)" ::: "memory");
  }
  __builtin_amdgcn_s_barrier();
  SB0();

  int t = 0;
  while (t < NT){
    KTILEO(0);
    KTILEO(1);
  }

  // ---- epilogue ----
  #pragma unroll
  for (int mt = 0; mt < 4; mt++){
    #pragma unroll
    for (int i = 0; i < 4; i++){
      int row = m0 + wr*64 + mt*16 + quad*4 + i;
      #pragma unroll
      for (int nt = 0; nt < 4; nt++){
        int col = n0 + wc*64 + nt*16 + l16;
        size_t idx = (size_t)row * N + col;
        float vv = acc[mt][nt][i];
        if (EPI == 1){
          ((unsigned short*)Cout)[idx] = f2b(gelu_fast(vv + bias[col]));
        } else {
          atomicAdd(&((float*)Cout)[idx], vv);
        }
      }
    }
  }
}

// ---------------- bf16 MFMA flash attention over M=1365 nodes ----------------
__global__ __launch_bounds__(256) void k_attn(
    const unsigned short* __restrict__ qb, const unsigned short* __restrict__ kb,
    const unsigned short* __restrict__ vtb, unsigned short* __restrict__ ob){
  __shared__ unsigned short Ks[64][64];
  __shared__ unsigned short Vt[64][64];
  __shared__ unsigned short Ps[4][16][64];
  int qt = blockIdx.x, bh = blockIdx.y;
  int b = bh / NH_, h = bh % NH_;
  int tid = threadIdx.x, wv = tid >> 6, lane = tid & 63;
  int quad = lane >> 4, l16 = lane & 15;

  int qm = qt*64 + wv*16 + l16;
  const unsigned short* qrow = qb + (size_t)(b*M_ + qm)*R_ + h*DH_;
  bf16x8 aq0 = *(const bf16x8*)(qrow + quad*8);
  bf16x8 aq1 = *(const bf16x8*)(qrow + 32 + quad*8);

  f32x4 oacc[4];
  #pragma unroll
  for (int db = 0; db < 4; db++) oacc[db] = 0.f;
  float mi[4], li[4];
  #pragma unroll
  for (int i = 0; i < 4; i++){ mi[i] = -1e30f; li[i] = 0.f; }

  for (int kt = 0; kt < 22; kt++){
    #pragma unroll
    for (int i = 0; i < 2; i++){
      int c = tid + i*256;
      int rowa = c >> 3, colc = (c & 7) * 8;
      *(uint4*)(&Ks[rowa][colc]) =
        *(const uint4*)(kb + (size_t)(b*M_ + kt*64 + rowa)*R_ + h*DH_ + colc);
      *(uint4*)(&Vt[rowa][colc]) =
        *(const uint4*)(vtb + ((size_t)bh*DH_ + rowa)*MPAD_ + kt*64 + colc);
    }
    __syncthreads();

    f32x4 s[4];
    #pragma unroll
    for (int nb = 0; nb < 4; nb++){
      s[nb] = 0.f;
      bf16x8 bk0 = *(const bf16x8*)(&Ks[nb*16 + l16][quad*8]);
      bf16x8 bk1 = *(const bf16x8*)(&Ks[nb*16 + l16][32 + quad*8]);
      s[nb] = __builtin_amdgcn_mfma_f32_16x16x32_bf16(aq0, bk0, s[nb], 0, 0, 0);
      s[nb] = __builtin_amdgcn_mfma_f32_16x16x32_bf16(aq1, bk1, s[nb], 0, 0, 0);
    }

    #pragma unroll
    for (int i = 0; i < 4; i++){
      float val[4];
      float mx = -1e30f;
      #pragma unroll
      for (int nb = 0; nb < 4; nb++){
        int gc = kt*64 + nb*16 + l16;
        val[nb] = (gc < M_) ? s[nb][i] * 0.125f : -1e30f;
        mx = fmaxf(mx, val[nb]);
      }
      mx = rmax16(mx);
      float mnew = fmaxf(mi[i], mx);
      float alpha = __expf(mi[i] - mnew);
      float rs = 0.f;
      #pragma unroll
      for (int nb = 0; nb < 4; nb++){
        float p = __expf(val[nb] - mnew);
        rs += p;
        Ps[wv][quad*4 + i][nb*16 + l16] = f2b(p);
      }
      rs = rsum16(rs);
      li[i] = li[i]*alpha + rs;
      mi[i] = mnew;
      #pragma unroll
      for (int db = 0; db < 4; db++) oacc[db][i] *= alpha;
    }

    #pragma unroll
    for (int ko = 0; ko < 2; ko++){
      bf16x8 ap = *(const bf16x8*)(&Ps[wv][l16][ko*32 + quad*8]);
      #pragma unroll
      for (int db = 0; db < 4; db++){
        bf16x8 bv = *(const bf16x8*)(&Vt[db*16 + l16][ko*32 + quad*8]);
        oacc[db] = __builtin_amdgcn_mfma_f32_16x16x32_bf16(ap, bv, oacc[db], 0, 0, 0);
      }
    }
    __syncthreads();
  }

  #pragma unroll
  for (int i = 0; i < 4; i++){
    int gm = qt*64 + wv*16 + quad*4 + i;
    if (gm < M_){
      float il = 1.f / li[i];
      #pragma unroll
      for (int db = 0; db < 4; db++)
        ob[(size_t)(b*M_ + gm)*R_ + h*DH_ + db*16 + l16] = f2b(oacc[db][i] * il);
    }
  }
}

// ---- scatter attn_out + residual -> xres; out = xres + b2 (MLP2 base); LN2 -> flat bf16 ----
__global__ __launch_bounds__(256) void k_scatter_ln2(
    const float* __restrict__ x, const float* __restrict__ attn,
    const float* __restrict__ lw, const float* __restrict__ lb,
    const float* __restrict__ b2,
    float* __restrict__ xres, unsigned short* __restrict__ flatb){
  int row  = blockIdx.x * 4 + (threadIdx.x >> 6);
  int lane = threadIdx.x & 63;
  int l  = row % 6;
  int hw = (row / 6) & 1023;
  int b  = row / 6144;
  int h = hw >> 5, w = hw & 31;
  int off = (4096 - (4096 >> (2*l))) / 3;
  int id  = off + (h >> l) * (32 >> l) + (w >> l);
  const float* ar = attn + ((size_t)b * M_ + id) * R_;
  const float* xr = x + (size_t)row * R_;
  float* orow = xres + (size_t)row * R_;
  float vv[6]; float s = 0.f;
  #pragma unroll
  for (int i = 0; i < 6; i++){
    int r = lane + i*64;
    float t = xr[r] + ar[r];
    vv[i] = t; s += t;
    orow[r] = t + b2[l*R_ + r];     // pre-fold bias: MLP2 partials atomicAdd onto this
  }
  s = wsum(s);
  float mu = s * (1.f/384.f);
  float qq = 0.f;
  #pragma unroll
  for (int i = 0; i < 6; i++){ float d = vv[i]-mu; qq += d*d; }
  qq = wsum(qq);
  float rs = rsqrtf(qq * (1.f/384.f) + 1e-5f);
  unsigned short* fr = flatb + (size_t)row * R_;
  #pragma unroll
  for (int i = 0; i < 6; i++){
    int r = lane + i*64;
    fr[r] = f2b((vv[i]-mu)*rs*lw[r] + lb[r]);
  }
}

extern "C" void kernel_launch(void* const* d_in, const int* in_sizes, int n_in,
                              void* d_out, int out_size, void* d_ws, size_t ws_size,
                              hipStream_t stream){
  const float* x    = (const float*)d_in[0];
  const float* ln1w = (const float*)d_in[1];
  const float* ln1b = (const float*)d_in[2];
  const float* ln2w = (const float*)d_in[3];
  const float* ln2b = (const float*)d_in[4];
  const float* wq   = (const float*)d_in[5];
  const float* bq   = (const float*)d_in[6];
  const float* wk   = (const float*)d_in[7];
  const float* bk   = (const float*)d_in[8];
  const float* wvv  = (const float*)d_in[9];
  const float* bv   = (const float*)d_in[10];
  const float* wo   = (const float*)d_in[11];
  const float* bo   = (const float*)d_in[12];
  const float* w1   = (const float*)d_in[13];
  const float* b1   = (const float*)d_in[14];
  const float* w2   = (const float*)d_in[15];
  const float* b2   = (const float*)d_in[16];
  float* out = (float*)d_out;

  // ---- workspace layout ----
  char* ws = (char*)d_ws;
  unsigned short* h1b = (unsigned short*)ws;                     // 8192*9216 bf16 (reuses region A)
  unsigned short* qb  = (unsigned short*)ws;
  unsigned short* kb  = qb + (size_t)BMR_ * R_;
  unsigned short* vtb = kb + (size_t)BMR_ * R_;
  unsigned short* ob  = vtb + (size_t)B_ * NH_ * DH_ * MPAD_;
  float* attn_o = (float*)(ob + (size_t)BMR_ * R_);
  size_t regA = ((size_t)8192 * HID_ * 2 + 255) & ~(size_t)255;
  char* p = ws + regA;
  float* uniqf = (float*)p;                   p += (size_t)BMR_ * R_ * 4;
  unsigned short* uniqb = (unsigned short*)p; p += (size_t)BMR_ * R_ * 2;
  unsigned short* wqkvt = (unsigned short*)p; p += (size_t)3 * R_ * R_ * 2;
  unsigned short* wot = (unsigned short*)p;   p += (size_t)R_ * R_ * 2;
  unsigned short* w1t = (unsigned short*)p;   p += (size_t)NE_ * HID_ * 2;
  unsigned short* w2t = (unsigned short*)p;   p += (size_t)NE_ * HID_ * 2;
  unsigned short* flatb = (unsigned short*)p; p += (size_t)NROW_ * R_ * 2;
  float* bqkv = (float*)p;                    p += (size_t)3 * R_ * 4;

  hipMemsetAsync(uniqf, 0, (size_t)BMR_ * R_ * 4, stream);
  hipMemsetAsync(vtb, 0, (size_t)B_ * NH_ * DH_ * MPAD_ * 2, stream);
  hipMemcpyAsync(bqkv,        bq, R_*4, hipMemcpyDeviceToDevice, stream);
  hipMemcpyAsync(bqkv + R_,   bk, R_*4, hipMemcpyDeviceToDevice, stream);
  hipMemcpyAsync(bqkv + 2*R_, bv, R_*4, hipMemcpyDeviceToDevice, stream);

  k_ln1_scatter<<<NROW_/4, 256, 0, stream>>>(x, ln1w, ln1b, uniqf);
  k_cvt<<<(BMR_*R_ + 255)/256, 256, 0, stream>>>(uniqf, uniqb, BMR_*R_);

  dim3 tb(32, 8);
  k_tcvt<<<dim3(R_/32, R_/32), tb, 0, stream>>>(wq, wqkvt, R_, R_);
  k_tcvt<<<dim3(R_/32, R_/32), tb, 0, stream>>>(wk, wqkvt + (size_t)R_*R_, R_, R_);
  k_tcvt<<<dim3(R_/32, R_/32), tb, 0, stream>>>(wvv, wqkvt + (size_t)2*R_*R_, R_, R_);
  k_tcvt<<<dim3(R_/32, R_/32), tb, 0, stream>>>(wo, wot, R_, R_);
  k_tcvt<<<dim3(HID_/32, NE_/32), tb, 0, stream>>>(w1, w1t, NE_, HID_);
  k_tcvt<<<dim3(NE_/32, HID_/32), tb, 0, stream>>>(w2, w2t, HID_, NE_);

  // merged QKV: N = 1152
  k_gemm<5><<<dim3(86, 9), 256, 0, stream>>>(uniqb, wqkvt, bqkv, qb, nullptr,
                                             kb, vtb, BMR_, 3*R_, R_);

  k_attn<<<dim3(22, 48), 256, 0, stream>>>(qb, kb, vtb, ob);

  k_gemm<0><<<dim3(86, 3), 256, 0, stream>>>(ob, wot, bo, attn_o, nullptr,
                                             nullptr, nullptr, BMR_, R_, R_);

  k_scatter_ln2<<<NROW_/4, 256, 0, stream>>>(x, attn_o, ln2w, ln2b, b2, out, flatb);

  // MLP up-proj: 8192x9216 = flatb(8192x2304) @ w1t^T, gelu -> bf16
  // grid 64x72 = 4608 blocks = 9.0 exact rounds at 2 blocks/CU (no tail)
  k_gemmO<1><<<dim3(64, 72), 256, 0, stream>>>(flatb, w1t, b1, h1b,
                                               8192, HID_, NE_, NE_);
  // MLP down-proj: split-K=2, fp32 atomicAdd onto out (= xres + b2)
  k_gemmO<3><<<dim3(64, 18, 2), 256, 0, stream>>>(h1b, w2t, nullptr, out,
                                                  8192, NE_, HID_, HID_/2);
}